// Round 11
// baseline (1563.863 us; speedup 1.0000x reference)
//
#include <hip/hip_runtime.h>
#include <hip/hip_bf16.h>
#include <stdint.h>

// ---------------------------------------------------------------------------
// DEER forward, MI355X. L=12, B=2, T=512, C=768, F=3072, M=B*T=1024.
// bf16 MFMA GEMMs (fp32 accum), analytic JVP, threefry2x32 Rademacher v.
// R11: R7 core (128x128, 4 waves 2Mx2N, depth-1 counted-vmcnt) with B taken
//      OUT of LDS: B fragments load global->VGPR (L2/L1-resident weights),
//      register-double-buffered (static bA/bB, rule-20-safe). LDS traffic
//      96->48 KB per block-K-tile; LDS 64->32 KB -> 3 blocks/CU.
//      A path (GLDS + swizzle) and epilogues byte-identical to R7.
// ---------------------------------------------------------------------------

typedef __bf16 bf16;
typedef __bf16 bf16x8 __attribute__((ext_vector_type(8)));
typedef float f32x4 __attribute__((ext_vector_type(4)));

#define LAY_A   1572864   // 2048*768
#define LAY_W   2359296   // 3072*768
#define LAY_Z   6291456   // 2048*3072
#define LAY_S   786432    // 1024*768

#define GLDS16(gp, lp) __builtin_amdgcn_global_load_lds(                      \
    (const __attribute__((address_space(1))) void*)(gp),                      \
    (__attribute__((address_space(3))) void*)(lp), 16, 0, 0)

#define WAITVM(N) asm volatile("s_waitcnt vmcnt(%0)" :: "n"(N) : "memory")
#define CFENCE()  asm volatile("" ::: "memory")

// ------------------------- threefry2x32 (host+device) ----------------------
#define TF_ROT(x0, x1, n) { x0 += x1; x1 = (x1 << n) | (x1 >> (32 - n)); x1 ^= x0; }
__host__ __device__ __forceinline__ void threefry2x32(
    uint32_t k1, uint32_t k2, uint32_t c0, uint32_t c1, uint32_t& o0, uint32_t& o1)
{
  const uint32_t ks2 = k1 ^ k2 ^ 0x1BD11BDAu;
  uint32_t x0 = c0 + k1, x1 = c1 + k2;
  TF_ROT(x0,x1,13) TF_ROT(x0,x1,15) TF_ROT(x0,x1,26) TF_ROT(x0,x1,6)
  x0 += k2;  x1 += ks2 + 1u;
  TF_ROT(x0,x1,17) TF_ROT(x0,x1,29) TF_ROT(x0,x1,16) TF_ROT(x0,x1,24)
  x0 += ks2; x1 += k1 + 2u;
  TF_ROT(x0,x1,13) TF_ROT(x0,x1,15) TF_ROT(x0,x1,26) TF_ROT(x0,x1,6)
  x0 += k1;  x1 += k2 + 3u;
  TF_ROT(x0,x1,17) TF_ROT(x0,x1,29) TF_ROT(x0,x1,16) TF_ROT(x0,x1,24)
  x0 += k2;  x1 += ks2 + 4u;
  TF_ROT(x0,x1,13) TF_ROT(x0,x1,15) TF_ROT(x0,x1,26) TF_ROT(x0,x1,6)
  x0 += ks2; x1 += k1 + 5u;
  o0 = x0; o1 = x1;
}

// --------------------- weight transpose fp32 -> bf16^T ---------------------
__global__ __launch_bounds__(256) void transpose_kernel(
    const float* __restrict__ w, bf16* __restrict__ wt, int R, int Cc)
{
  __shared__ float tile[32][33];
  const int l = blockIdx.z;
  const float* wp = w + (size_t)l * R * Cc;
  bf16* wtp = wt + (size_t)l * R * Cc;
  const int c0 = blockIdx.x * 32;
  const int r0 = blockIdx.y * 32;
  const int tx = threadIdx.x & 31, ty = threadIdx.x >> 5;
  #pragma unroll
  for (int q = 0; q < 4; ++q)
    tile[ty + q * 8][tx] = wp[(size_t)(r0 + ty + q * 8) * Cc + c0 + tx];
  __syncthreads();
  #pragma unroll
  for (int q = 0; q < 4; ++q)
    wtp[(size_t)(c0 + ty + q * 8) * R + r0 + tx] = (bf16)tile[tx][ty + q * 8];
}

// ------------------------------ gelu helper --------------------------------
__device__ __forceinline__ void gelu2(float z, float& h, float& dg)
{
  const float z2 = z * z;
  const float u = 0.7978845608028654f * (z + 0.044715f * z2 * z);
  const float t = tanhf(u);
  h = 0.5f * z * (1.f + t);
  dg = 0.5f * (1.f + t) +
       0.5f * z * (1.f - t * t) * 0.7978845608028654f * (1.f + 0.134145f * z2);
}

// ------------------------------ GEMM core ----------------------------------
// 128x128 tile, BK=64, 256 threads = 4 waves (2M x 2N), per-wave 64x64 out.
// A: GLDS-staged into LDS (R7 layout/swizzle). B: direct global->VGPR
// fragment loads (weights L2/L1-resident), register double-buffered.
// Depth-1 counted-vmcnt pipeline: 12 vm-ops per tile (8 B + 4 A).
// MODE 0: gemm1 warm  (M=1024): zh = gelu(acc + b1), all rows.
// MODE 1: gemm1 iter  (M=2048 interleaved): even h=gelu(z), odd dh=dg*dz.
// MODE 2: gemm2 warm : states[l+1] = acc + b2 + x0.
// MODE 3: gemm2 iter  (interleaved): even res, odd A = 1 + acc*v.
template <int MODE>
__global__ __launch_bounds__(256, 3) void gemm_dbuf(
    const bf16* __restrict__ Abase, const bf16* __restrict__ Bbase,
    bf16* __restrict__ zh_out, float* __restrict__ states,
    float* __restrict__ resA, const bf16* __restrict__ vbuf,
    const float* __restrict__ bias1, const float* __restrict__ b2,
    const float* __restrict__ x0, int Mt)
{
  constexpr int LDAB  = (MODE <= 1) ? 768 : 3072;
  constexpr int NKT   = (MODE <= 1) ? 12 : 48;      // K/64 (even)
  constexpr int NTN   = (MODE <= 1) ? 24 : 6;       // N/128
  constexpr int ABYTES = 16384;             // A tile: 128 rows x 128 B
  constexpr size_t LSA = (MODE <= 1) ? LAY_A : LAY_Z;

  __shared__ __align__(16) char lds[2][ABYTES];  // 32 KiB double buffer

  const int tid  = threadIdx.x;
  const int lane = tid & 63;
  const int wid  = tid >> 6;           // 0..3
  const int wr   = wid >> 1;           // 0..1  (M half)
  const int wc   = wid & 1;            // 0..1  (N half)
  const int r16  = lane & 15;
  const int hi   = lane >> 4;          // 0..3

  // T1: XCD-aware bijective swizzle (grids are multiples of 8)
  const int nwg = gridDim.x;
  const int bid = blockIdx.x;
  const int swz = (bid & 7) * (nwg >> 3) + (bid >> 3);
  const int per_l = Mt * NTN;
  const int l   = swz / per_l;
  const int rr_ = swz - l * per_l;
  const int mt  = rr_ / NTN;
  const int nt  = rr_ - mt * NTN;
  const int m0  = mt * 128, n0 = nt * 128;

  const bf16* A = Abase + (size_t)l * LSA   + (size_t)m0 * LDAB;
  const bf16* B = Bbase + (size_t)l * LAY_W + (size_t)n0 * LDAB;

  const int rsub = lane >> 3;               // 0..7 row within chunk
  const int c8   = (lane & 7) ^ rsub;       // swizzled 16B slot (involution)

  // A staging pointers (ptr-increment, 64 elems = 128 B per K-tile)
  const bf16* ag[4];
  #pragma unroll
  for (int j = 0; j < 4; ++j)
    ag[j] = A + (size_t)((j * 4 + wid) * 8 + rsub) * LDAB + c8 * 8;
  auto STAGEA = [&](char* dst) {
    #pragma unroll
    for (int j = 0; j < 4; ++j) {
      GLDS16(ag[j], dst + (j * 4 + wid) * 1024);
      ag[j] += 64;
    }
  };

  // B fragment row pointers (4 rows per lane), advanced 64 elems per K-tile
  const bf16* bp[4];
  #pragma unroll
  for (int ni = 0; ni < 4; ++ni)
    bp[ni] = B + (size_t)(wc * 64 + ni * 16 + r16) * LDAB + hi * 8;
  auto BFLOAD = [&](bf16x8* dst) {        // dst[kk*4+ni], 8 loads
    #pragma unroll
    for (int ni = 0; ni < 4; ++ni) {
      dst[ni]     = *(const bf16x8*)(bp[ni]);
      dst[4 + ni] = *(const bf16x8*)(bp[ni] + 32);
      bp[ni] += 64;
    }
  };

  f32x4 acc[4][4] = {};
  const int xw = (r16 & 7) << 4;          // A read-side XOR (matches staging)

  auto COMPUTE = [&](const char* As, const bf16x8* bfr) {
    #pragma unroll
    for (int kk = 0; kk < 2; ++kk) {
      const int cb = kk * 64;
      bf16x8 afrag[4];
      #pragma unroll
      for (int q = 0; q < 4; ++q) {
        const int rm = wr * 64 + q * 16 + r16;
        afrag[q] = *(const bf16x8*)(As + rm * 128 + ((cb + hi * 16) ^ xw));
      }
      #pragma unroll
      for (int q = 0; q < 4; ++q)
        #pragma unroll
        for (int ni = 0; ni < 4; ++ni)
          acc[q][ni] = __builtin_amdgcn_mfma_f32_16x16x32_bf16(
              afrag[q], bfr[kk * 4 + ni], acc[q][ni], 0, 0, 0);
    }
  };

  // ---- depth-1 counted-vmcnt pipeline, 12 vm-ops/tile, static reg dbuf ----
  bf16x8 bA[8], bB[8];
  BFLOAD(bA); STAGEA(lds[0]);          // tile 0
  BFLOAD(bB); STAGEA(lds[1]);          // tile 1
  WAITVM(12);                          // tile 0 landed; tile 1 in flight
  __builtin_amdgcn_s_barrier();
  CFENCE();
  COMPUTE(lds[0], bA);                 // tile 0
  #pragma unroll 1
  for (int tp = 1; tp + 1 < NKT; tp += 2) {
    // stage tile tp+1 (even -> lds[0]/bA); compute tile tp (odd -> lds[1]/bB)
    CFENCE();
    __builtin_amdgcn_s_barrier();      // all waves done reading lds[0]
    CFENCE();
    BFLOAD(bA); STAGEA(lds[0]);
    WAITVM(12);                        // tile tp landed; tp+1 in flight
    __builtin_amdgcn_s_barrier();
    CFENCE();
    COMPUTE(lds[1], bB);
    // stage tile tp+2 (odd -> lds[1]/bB); compute tile tp+1 (even lds[0]/bA)
    CFENCE();
    __builtin_amdgcn_s_barrier();      // all waves done reading lds[1]
    CFENCE();
    if (tp + 2 < NKT) {
      BFLOAD(bB); STAGEA(lds[1]);
      WAITVM(12);
    } else {
      WAITVM(0);
    }
    __builtin_amdgcn_s_barrier();
    CFENCE();
    COMPUTE(lds[0], bA);
  }
  // tail: tile NKT-1 (odd -> lds[1]/bB)
  CFENCE();
  __builtin_amdgcn_s_barrier();
  CFENCE();
  WAITVM(0);
  __builtin_amdgcn_s_barrier();
  CFENCE();
  COMPUTE(lds[1], bB);

  // ------------------------------ epilogue ---------------------------------
  #pragma unroll
  for (int mi = 0; mi < 4; ++mi) {
    const int row0 = m0 + wr * 64 + mi * 16 + hi * 4;
    #pragma unroll
    for (int ni = 0; ni < 4; ++ni) {
      const int col = n0 + wc * 64 + ni * 16 + r16;
      if (MODE == 0) {                  // warm gemm1: h = gelu(z), all rows
        bf16* Cp = zh_out + (size_t)l * LAY_Z;
        const float bias = bias1[l * 3072 + col];
        #pragma unroll
        for (int r = 0; r < 4; ++r) {
          float h, dg;
          gelu2(acc[mi][ni][r] + bias, h, dg);
          Cp[(size_t)(row0 + r) * 3072 + col] = (bf16)h;
        }
      } else if (MODE == 1) {           // iter gemm1: row pairs (z, dz)
        bf16* Cp = zh_out + (size_t)l * LAY_Z;
        const float bias = bias1[l * 3072 + col];
        #pragma unroll
        for (int p = 0; p < 2; ++p) {
          float h, dg;
          gelu2(acc[mi][ni][2 * p] + bias, h, dg);
          Cp[(size_t)(row0 + 2 * p) * 3072 + col] = (bf16)h;
          Cp[(size_t)(row0 + 2 * p + 1) * 3072 + col] =
              (bf16)(dg * acc[mi][ni][2 * p + 1]);
        }
      } else if (MODE == 2) {           // warm gemm2
        float* Sp = states + (size_t)(l + 1) * LAY_S;
        const float bb = b2[l * 768 + col];
        #pragma unroll
        for (int r = 0; r < 4; ++r)
          Sp[(size_t)(row0 + r) * 768 + col] =
              acc[mi][ni][r] + bb + x0[(size_t)(row0 + r) * 768 + col];
      } else {                          // iter gemm2: row pairs (res, Adiag)
        float* Rp = resA + (size_t)l * LAY_A;
        const float bb = b2[l * 768 + col];
        #pragma unroll
        for (int p = 0; p < 2; ++p) {
          const int tok = (row0 >> 1) + p;          // rows row0+2p, +2p+1
          Rp[(size_t)tok * 768 + col] = acc[mi][ni][2 * p] + bb
              + states[(size_t)l * LAY_S + (size_t)tok * 768 + col]
              - states[(size_t)(l + 1) * LAY_S + (size_t)tok * 768 + col];
          const float vv = (float)vbuf[(size_t)l * LAY_S +
                                       (size_t)tok * 768 + col];
          Rp[LAY_S + (size_t)tok * 768 + col] =
              1.0f + acc[mi][ni][2 * p + 1] * vv;
        }
      }
    }
  }
}

// ------------------------------- LayerNorm ---------------------------------
__global__ __launch_bounds__(256) void ln_warm_kernel(
    const float* __restrict__ x0, const float* __restrict__ g,
    const float* __restrict__ beta, bf16* __restrict__ a_buf)
{
  const int row = blockIdx.x * 4 + (threadIdx.x >> 6);
  const int lane = threadIdx.x & 63;
  const float* x = x0 + (size_t)row * 768;
  float xl[12];
  float s1 = 0.f, s2 = 0.f;
  #pragma unroll
  for (int j = 0; j < 12; ++j) {
    float t = x[lane + 64 * j];
    xl[j] = t; s1 += t; s2 += t * t;
  }
  #pragma unroll
  for (int off = 1; off < 64; off <<= 1) {
    s1 += __shfl_xor(s1, off);
    s2 += __shfl_xor(s2, off);
  }
  const float mu = s1 * (1.f / 768.f);
  const float var = s2 * (1.f / 768.f) - mu * mu;
  const float rstd = rsqrtf(var + 1e-5f);
  float xh[12];
  #pragma unroll
  for (int j = 0; j < 12; ++j) xh[j] = (xl[j] - mu) * rstd;
  for (int l = 0; l < 12; ++l) {
    const float* gp = g + l * 768;
    const float* bp = beta + l * 768;
    bf16* ap = a_buf + (size_t)l * LAY_A + (size_t)row * 768;
    #pragma unroll
    for (int j = 0; j < 12; ++j) {
      const int c = lane + 64 * j;
      ap[c] = (bf16)(xh[j] * gp[c] + bp[c]);
    }
  }
}

// iter: LN + LN-JVP with tangent v (v generated inline via threefry).
// Writes interleaved rows: token row -> a at 2*row, du at 2*row+1.
__global__ __launch_bounds__(256) void ln_iter_kernel(
    const float* __restrict__ states, bf16* __restrict__ vbuf,
    const float* __restrict__ g, const float* __restrict__ beta,
    bf16* __restrict__ a_buf, uint32_t k1, uint32_t k2)
{
  const int gr = blockIdx.x * 4 + (threadIdx.x >> 6);
  const int l = gr >> 10;
  const int row = gr & 1023;
  const int lane = threadIdx.x & 63;
  const float* x = states + (size_t)l * LAY_S + (size_t)row * 768;
  bf16* vp = vbuf + (size_t)gr * 768;
  float xl[12], vl[12];
  float s1 = 0.f, s2 = 0.f, sv = 0.f, sxv = 0.f;
  #pragma unroll
  for (int j = 0; j < 12; ++j) {
    const int c = lane + 64 * j;
    const float t = x[c];
    uint32_t o0, o1;
    threefry2x32(k1, k2, 0u, (uint32_t)gr * 768u + (uint32_t)c, o0, o1);
    const float u = ((o0 ^ o1) & 0x80000000u) ? 1.0f : -1.0f;
    vp[c] = (bf16)u;
    xl[j] = t; vl[j] = u;
    s1 += t; s2 += t * t; sv += u; sxv += t * u;
  }
  #pragma unroll
  for (int off = 1; off < 64; off <<= 1) {
    s1 += __shfl_xor(s1, off); s2 += __shfl_xor(s2, off);
    sv += __shfl_xor(sv, off); sxv += __shfl_xor(sxv, off);
  }
  const float mu = s1 * (1.f / 768.f);
  const float var = s2 * (1.f / 768.f) - mu * mu;
  const float rstd = rsqrtf(var + 1e-5f);
  const float mv = sv * (1.f / 768.f);
  const float mhv = rstd * (sxv * (1.f / 768.f) - mu * mv);
  const float* gp = g + l * 768;
  const float* bp = beta + l * 768;
  bf16* ap = a_buf + (size_t)l * LAY_A + (size_t)(2 * row) * 768;
  bf16* dp = ap + 768;
  #pragma unroll
  for (int j = 0; j < 12; ++j) {
    const int c = lane + 64 * j;
    const float xh = (xl[j] - mu) * rstd;
    ap[c] = (bf16)(xh * gp[c] + bp[c]);
    dp[c] = (bf16)(rstd * ((vl[j] - mv) - xh * mhv) * gp[c]);
  }
}

// --------------------------- scan + state update ---------------------------
__global__ __launch_bounds__(256) void scan_kernel(
    const float* __restrict__ resA, float* __restrict__ states)
{
  const size_t i = (size_t)blockIdx.x * 256 + threadIdx.x;
  float run = resA[i];
  states[LAY_S + i] += run;
  #pragma unroll
  for (int l = 1; l < 12; ++l) {
    const float b  = resA[(size_t)l * LAY_A + i];
    const float Aa = resA[(size_t)l * LAY_A + LAY_S + i];
    run = b + Aa * run;
    states[(size_t)(l + 1) * LAY_S + i] += run;
  }
}

// ------------------------------- launcher ----------------------------------
extern "C" void kernel_launch(void* const* d_in, const int* in_sizes, int n_in,
                              void* d_out, int out_size, void* d_ws, size_t ws_size,
                              hipStream_t stream)
{
  const float* x0   = (const float*)d_in[0];
  const float* w1   = (const float*)d_in[1];
  const float* b1   = (const float*)d_in[2];
  const float* w2   = (const float*)d_in[3];
  const float* b2   = (const float*)d_in[4];
  const float* g    = (const float*)d_in[5];
  const float* beta = (const float*)d_in[6];

  char* ws = (char*)d_ws;
  size_t off = 0;
  auto alloc = [&](size_t bytes) -> void* {
    void* p = ws + off;
    off += (bytes + 255) & ~(size_t)255;
    return p;
  };
  bf16*  w1t    = (bf16*)alloc(2ULL * 12 * LAY_W);
  bf16*  w2t    = (bf16*)alloc(2ULL * 12 * LAY_W);
  float* states = (float*)alloc(4ULL * 13 * LAY_S);
  bf16*  a_buf  = (bf16*)alloc(2ULL * 12 * LAY_A);
  bf16*  zh     = (bf16*)alloc(2ULL * 12 * LAY_Z);
  float* resA   = (float*)alloc(4ULL * 12 * LAY_A);
  bf16*  vbuf   = (bf16*)alloc(2ULL * 12 * LAY_S);

  transpose_kernel<<<dim3(96, 24, 12), 256, 0, stream>>>(w1, w1t, 768, 3072);
  transpose_kernel<<<dim3(24, 96, 12), 256, 0, stream>>>(w2, w2t, 3072, 768);
  hipMemcpyAsync(states, x0, 4ULL * LAY_S, hipMemcpyDeviceToDevice, stream);

  // warm start: states[l+1] = block_l(x0)
  ln_warm_kernel<<<256, 256, 0, stream>>>(x0, g, beta, a_buf);
  gemm_dbuf<0><<<2304, 256, 0, stream>>>(a_buf, w1t, zh, states, resA, vbuf,
                                         b1, b2, x0, 8);
  gemm_dbuf<2><<<576, 256, 0, stream>>>(zh, w2t, nullptr, states, resA, vbuf,
                                        b1, b2, x0, 8);

  for (int it = 0; it < 2; ++it) {
    uint32_t k1, k2;
    threefry2x32(0u, 42u, 0u, (uint32_t)it, k1, k2);
    ln_iter_kernel<<<3072, 256, 0, stream>>>(states, vbuf, g, beta, a_buf,
                                             k1, k2);
    gemm_dbuf<1><<<4608, 256, 0, stream>>>(a_buf, w1t, zh, states, resA, vbuf,
                                           b1, b2, x0, 16);
    gemm_dbuf<3><<<1152, 256, 0, stream>>>(zh, w2t, nullptr, states, resA, vbuf,
                                           b1, b2, x0, 16);
    scan_kernel<<<3072, 256, 0, stream>>>(resA, states);
  }

  hipMemcpyAsync(d_out, states + 12ULL * LAY_S, 4ULL * LAY_S,
                 hipMemcpyDeviceToDevice, stream);
}

// Round 12
// 1051.952 us; speedup vs baseline: 1.4866x; 1.4866x over previous
//
#include <hip/hip_runtime.h>
#include <hip/hip_bf16.h>
#include <stdint.h>

// ---------------------------------------------------------------------------
// DEER forward, MI355X. L=12, B=2, T=512, C=768, F=3072, M=B*T=1024.
// bf16 MFMA GEMMs (fp32 accum), analytic JVP, threefry2x32 Rademacher v.
// R12: gemm1 (MODE0/1) -> m201-style 8-phase 256x256xBK64 schedule
//      (512 thr, 8 waves 2Mx4N, wave 128x64, 128KB LDS dbuf, per-phase
//      {ds_read quadrant | 2-4 GLDS stage | 16 MFMA}, two barriers/phase,
//      boundary vmcnt(0) with nothing younger in flight). gemm2 (MODE2/3)
//      stays the R7-proven 128x128 2-blocks/CU kernel (1036us baseline).
//      K-accumulation order unchanged -> numerics identical (absmax 0.1875).
// ---------------------------------------------------------------------------

typedef __bf16 bf16;
typedef __bf16 bf16x8 __attribute__((ext_vector_type(8)));
typedef float f32x4 __attribute__((ext_vector_type(4)));

#define LAY_A   1572864   // 2048*768
#define LAY_W   2359296   // 3072*768
#define LAY_Z   6291456   // 2048*3072
#define LAY_S   786432    // 1024*768

#define GLDS16(gp, lp) __builtin_amdgcn_global_load_lds(                      \
    (const __attribute__((address_space(1))) void*)(gp),                      \
    (__attribute__((address_space(3))) void*)(lp), 16, 0, 0)

#define WAITVM(N) asm volatile("s_waitcnt vmcnt(%0)" :: "n"(N) : "memory")
#define LGKM0()   asm volatile("s_waitcnt lgkmcnt(0)" ::: "memory")
#define CFENCE()  asm volatile("" ::: "memory")

// ------------------------- threefry2x32 (host+device) ----------------------
#define TF_ROT(x0, x1, n) { x0 += x1; x1 = (x1 << n) | (x1 >> (32 - n)); x1 ^= x0; }
__host__ __device__ __forceinline__ void threefry2x32(
    uint32_t k1, uint32_t k2, uint32_t c0, uint32_t c1, uint32_t& o0, uint32_t& o1)
{
  const uint32_t ks2 = k1 ^ k2 ^ 0x1BD11BDAu;
  uint32_t x0 = c0 + k1, x1 = c1 + k2;
  TF_ROT(x0,x1,13) TF_ROT(x0,x1,15) TF_ROT(x0,x1,26) TF_ROT(x0,x1,6)
  x0 += k2;  x1 += ks2 + 1u;
  TF_ROT(x0,x1,17) TF_ROT(x0,x1,29) TF_ROT(x0,x1,16) TF_ROT(x0,x1,24)
  x0 += ks2; x1 += k1 + 2u;
  TF_ROT(x0,x1,13) TF_ROT(x0,x1,15) TF_ROT(x0,x1,26) TF_ROT(x0,x1,6)
  x0 += k1;  x1 += k2 + 3u;
  TF_ROT(x0,x1,17) TF_ROT(x0,x1,29) TF_ROT(x0,x1,16) TF_ROT(x0,x1,24)
  x0 += k2;  x1 += ks2 + 4u;
  TF_ROT(x0,x1,13) TF_ROT(x0,x1,15) TF_ROT(x0,x1,26) TF_ROT(x0,x1,6)
  x0 += ks2; x1 += k1 + 5u;
  o0 = x0; o1 = x1;
}

// --------------------- weight transpose fp32 -> bf16^T ---------------------
__global__ __launch_bounds__(256) void transpose_kernel(
    const float* __restrict__ w, bf16* __restrict__ wt, int R, int Cc)
{
  __shared__ float tile[32][33];
  const int l = blockIdx.z;
  const float* wp = w + (size_t)l * R * Cc;
  bf16* wtp = wt + (size_t)l * R * Cc;
  const int c0 = blockIdx.x * 32;
  const int r0 = blockIdx.y * 32;
  const int tx = threadIdx.x & 31, ty = threadIdx.x >> 5;
  #pragma unroll
  for (int q = 0; q < 4; ++q)
    tile[ty + q * 8][tx] = wp[(size_t)(r0 + ty + q * 8) * Cc + c0 + tx];
  __syncthreads();
  #pragma unroll
  for (int q = 0; q < 4; ++q)
    wtp[(size_t)(c0 + ty + q * 8) * R + r0 + tx] = (bf16)tile[tx][ty + q * 8];
}

// ------------------------------ gelu helper --------------------------------
__device__ __forceinline__ void gelu2(float z, float& h, float& dg)
{
  const float z2 = z * z;
  const float u = 0.7978845608028654f * (z + 0.044715f * z2 * z);
  const float t = tanhf(u);
  h = 0.5f * z * (1.f + t);
  dg = 0.5f * (1.f + t) +
       0.5f * z * (1.f - t * t) * 0.7978845608028654f * (1.f + 0.134145f * z2);
}

// ---------------------- gemm1: 8-phase 256x256 kernel ----------------------
// BK=64, 512 threads = 8 waves (2M x 4N), per-wave 128x64, acc[8][4].
// LDS 2 x (A 32KB | B 32KB) = 128KB. 128B rows, 8x16B slot XOR swizzle
// (R7-proven, conflict-free). Per K-tile: 4 phases, each
// {ds_read quadrant; stage GLDS; bar; lgkm0; setprio MFMA16 setprio; bar}.
// Tile t+1's 8 GLDS issue in t's ph0/ph1; boundary vmcnt(0) at end of ph3
// has nothing younger in flight (no over-drain, loads >=2 phases old).
// MODE 0: warm (M=1024): zh = gelu(acc + b1), all rows.
// MODE 1: iter (M=2048 interleaved): even h=gelu(z), odd dh=dg*dz.
template <int MODE>
__global__ __launch_bounds__(512, 2) void gemm1_8p(
    const bf16* __restrict__ Abase, const bf16* __restrict__ Bbase,
    bf16* __restrict__ zh_out, const float* __restrict__ bias1, int Mt)
{
  constexpr int LDAB = 768;
  constexpr int NKT  = 12;              // K/64
  constexpr int NTN  = 12;              // N/256
  constexpr int HB   = 32768;           // A/B half size in bytes

  __shared__ __align__(16) char lds[2][2 * HB];   // 128 KiB

  const int tid  = threadIdx.x;
  const int lane = tid & 63;
  const int wid  = tid >> 6;           // 0..7
  const int wr   = wid >> 2;           // 0..1  (M half of 256)
  const int wc   = wid & 3;            // 0..3  (N quarter of 256)
  const int r16  = lane & 15;
  const int hi   = lane >> 4;          // 0..3

  // T1 XCD swizzle (grids are multiples of 8)
  const int nwg = gridDim.x;
  const int bid = blockIdx.x;
  const int swz = (bid & 7) * (nwg >> 3) + (bid >> 3);
  const int per_l = Mt * NTN;
  const int l   = swz / per_l;
  const int rr_ = swz - l * per_l;
  const int mt  = rr_ / NTN;
  const int nt  = rr_ - mt * NTN;
  const int m0  = mt * 256, n0 = nt * 256;

  const bf16* A = Abase + (size_t)l * LAY_A + (size_t)m0 * LDAB;
  const bf16* B = Bbase + (size_t)l * LAY_W + (size_t)n0 * LDAB;

  // staging: chunk = j*8+wid (1 KiB = 8 rows x 128B); lane -> row/slot
  const int rsub = lane >> 3;               // row within chunk
  const int c8   = (lane & 7) ^ rsub;       // swizzled 16B slot (involution)
  const bf16* ag[4];
  const bf16* bg[4];
  #pragma unroll
  for (int j = 0; j < 4; ++j) {
    const int chunk = j * 8 + wid;
    ag[j] = A + (size_t)(chunk * 8 + rsub) * LDAB + c8 * 8;
    bg[j] = B + (size_t)(chunk * 8 + rsub) * LDAB + c8 * 8;
  }
  auto SHALF0 = [&](char* buf) {            // A,B chunks j=0,1
    #pragma unroll
    for (int j = 0; j < 2; ++j) {
      GLDS16(ag[j], buf + (j * 8 + wid) * 1024);
      GLDS16(bg[j], buf + HB + (j * 8 + wid) * 1024);
    }
  };
  auto SHALF1 = [&](char* buf) {            // A,B chunks j=2,3; advance ptrs
    #pragma unroll
    for (int j = 2; j < 4; ++j) {
      GLDS16(ag[j], buf + (j * 8 + wid) * 1024);
      GLDS16(bg[j], buf + HB + (j * 8 + wid) * 1024);
    }
    #pragma unroll
    for (int j = 0; j < 4; ++j) { ag[j] += 64; bg[j] += 64; }
  };

  f32x4 acc[8][4] = {};
  bf16x8 bfr[4], af[4];
  const int xw = (r16 & 7) << 4;            // read-side XOR

  auto DSB = [&](const char* buf, int kk) {
    const char* Bs = buf + HB;
    #pragma unroll
    for (int ni = 0; ni < 4; ++ni) {
      const int rn = wc * 64 + ni * 16 + r16;
      bfr[ni] = *(const bf16x8*)(Bs + rn * 128 + ((kk * 64 + hi * 16) ^ xw));
    }
  };
  auto DSA = [&](const char* buf, int mh, int kk) {
    #pragma unroll
    for (int q = 0; q < 4; ++q) {
      const int rm = wr * 128 + (mh * 4 + q) * 16 + r16;
      af[q] = *(const bf16x8*)(buf + rm * 128 + ((kk * 64 + hi * 16) ^ xw));
    }
  };
  auto MF = [&](int mh) {
    __builtin_amdgcn_s_setprio(1);
    #pragma unroll
    for (int q = 0; q < 4; ++q)
      #pragma unroll
      for (int ni = 0; ni < 4; ++ni)
        acc[mh * 4 + q][ni] = __builtin_amdgcn_mfma_f32_16x16x32_bf16(
            af[q], bfr[ni], acc[mh * 4 + q][ni], 0, 0, 0);
    __builtin_amdgcn_s_setprio(0);
  };

  // prologue: stage tile 0
  SHALF0(lds[0]);
  SHALF1(lds[0]);
  WAITVM(0);                           // tile 0 landed (nothing younger)
  __builtin_amdgcn_s_barrier();
  CFENCE();

  #pragma unroll 1
  for (int t = 0; t < NKT; ++t) {
    char* cur = lds[t & 1];
    char* nxt = lds[(t & 1) ^ 1];
    const bool more = (t + 1 < NKT);
    // phase 0: quadrant (mh=0, kk=0); stage half 0 of tile t+1
    DSB(cur, 0); DSA(cur, 0, 0);
    if (more) SHALF0(nxt);
    CFENCE(); __builtin_amdgcn_s_barrier(); LGKM0();
    MF(0);
    CFENCE(); __builtin_amdgcn_s_barrier(); CFENCE();
    // phase 1: (mh=1, kk=0); stage half 1 of tile t+1
    DSA(cur, 1, 0);
    if (more) SHALF1(nxt);
    CFENCE(); __builtin_amdgcn_s_barrier(); LGKM0();
    MF(1);
    CFENCE(); __builtin_amdgcn_s_barrier(); CFENCE();
    // phase 2: (mh=0, kk=1)
    DSB(cur, 1); DSA(cur, 0, 1);
    CFENCE(); __builtin_amdgcn_s_barrier(); LGKM0();
    MF(0);
    CFENCE(); __builtin_amdgcn_s_barrier(); CFENCE();
    // phase 3: (mh=1, kk=1); boundary wait for tile t+1
    DSA(cur, 1, 1);
    CFENCE(); __builtin_amdgcn_s_barrier(); LGKM0();
    MF(1);
    if (more) {
      WAITVM(0);                       // tile t+1 landed (issued ph0/ph1)
      CFENCE(); __builtin_amdgcn_s_barrier(); CFENCE();
    }
  }

  // ------------------------------ epilogue ---------------------------------
  bf16* Cp = zh_out + (size_t)l * LAY_Z;
  #pragma unroll
  for (int mi = 0; mi < 8; ++mi) {
    const int row0 = m0 + wr * 128 + mi * 16 + hi * 4;
    #pragma unroll
    for (int ni = 0; ni < 4; ++ni) {
      const int col = n0 + wc * 64 + ni * 16 + r16;
      const float bias = bias1[l * 3072 + col];
      if (MODE == 0) {                  // warm: h = gelu(z), all rows
        #pragma unroll
        for (int r = 0; r < 4; ++r) {
          float h, dg;
          gelu2(acc[mi][ni][r] + bias, h, dg);
          Cp[(size_t)(row0 + r) * 3072 + col] = (bf16)h;
        }
      } else {                          // iter: row pairs (z, dz)
        #pragma unroll
        for (int p = 0; p < 2; ++p) {
          float h, dg;
          gelu2(acc[mi][ni][2 * p] + bias, h, dg);
          Cp[(size_t)(row0 + 2 * p) * 3072 + col] = (bf16)h;
          Cp[(size_t)(row0 + 2 * p + 1) * 3072 + col] =
              (bf16)(dg * acc[mi][ni][2 * p + 1]);
        }
      }
    }
  }
}

// ------------------- gemm2: R7-proven 128x128 kernel -----------------------
// 128x128 tile, BK=64, 256 threads = 4 waves (2M x 2N), per-wave 64x64 out.
// Depth-1 counted-vmcnt pipeline over 2 LDS buffers (64 KiB -> 2 blocks/CU).
// MODE 2: gemm2 warm : states[l+1] = acc + b2 + x0.
// MODE 3: gemm2 iter  (interleaved): even res, odd A = 1 + acc*v.
template <int MODE>
__global__ __launch_bounds__(256, 2) void gemm_dbuf(
    const bf16* __restrict__ Abase, const bf16* __restrict__ Bbase,
    float* __restrict__ states, float* __restrict__ resA,
    const bf16* __restrict__ vbuf, const float* __restrict__ b2,
    const float* __restrict__ x0, int Mt)
{
  constexpr int LDAB  = 3072;
  constexpr int NKT   = 48;                 // K/64
  constexpr int NTN   = 6;                  // N/128
  constexpr int NCH   = 8;                  // loads per thread per tile
  constexpr int ABYTES = 16384;
  constexpr int TILE  = ABYTES + 16384;     // 32 KiB

  __shared__ __align__(16) char lds[2][TILE];

  const int tid  = threadIdx.x;
  const int lane = tid & 63;
  const int wid  = tid >> 6;
  const int wr   = wid >> 1;
  const int wc   = wid & 1;
  const int r16  = lane & 15;
  const int hi   = lane >> 4;

  const int nwg = gridDim.x;
  const int bid = blockIdx.x;
  const int swz = (bid & 7) * (nwg >> 3) + (bid >> 3);
  const int per_l = Mt * NTN;
  const int l   = swz / per_l;
  const int rr_ = swz - l * per_l;
  const int mt  = rr_ / NTN;
  const int nt  = rr_ - mt * NTN;
  const int m0  = mt * 128, n0 = nt * 128;

  const bf16* A = Abase + (size_t)l * LAY_Z + (size_t)m0 * LDAB;
  const bf16* B = Bbase + (size_t)l * LAY_W + (size_t)n0 * LDAB;

  const int rsub = lane >> 3;
  const int c8   = (lane & 7) ^ rsub;
  auto STAGE = [&](char* dst, int kt) {
    #pragma unroll
    for (int j = 0; j < NCH; ++j) {
      const int chunk = j * 4 + wid;
      if (chunk < 16) {
        const int row = chunk * 8 + rsub;
        GLDS16(A + (size_t)row * LDAB + kt + c8 * 8, dst + chunk * 1024);
      } else {
        const int row = (chunk - 16) * 8 + rsub;
        GLDS16(B + (size_t)row * LDAB + kt + c8 * 8,
               dst + ABYTES + (chunk - 16) * 1024);
      }
    }
  };

  f32x4 acc[4][4] = {};

  auto COMPUTE = [&](const char* buf) {
    const char* As = buf;
    const char* Bs = buf + ABYTES;
    const int xw = (r16 & 7) << 4;
    #pragma unroll
    for (int kk = 0; kk < 2; ++kk) {
      const int cb = kk * 64;
      bf16x8 bfrag[4];
      #pragma unroll
      for (int ni = 0; ni < 4; ++ni) {
        const int rn = wc * 64 + ni * 16 + r16;
        bfrag[ni] = *(const bf16x8*)(Bs + rn * 128 + ((cb + hi * 16) ^ xw));
      }
      bf16x8 afrag[4];
      #pragma unroll
      for (int q = 0; q < 4; ++q) {
        const int rm = wr * 64 + q * 16 + r16;
        afrag[q] = *(const bf16x8*)(As + rm * 128 + ((cb + hi * 16) ^ xw));
      }
      #pragma unroll
      for (int q = 0; q < 4; ++q)
        #pragma unroll
        for (int ni = 0; ni < 4; ++ni)
          acc[q][ni] = __builtin_amdgcn_mfma_f32_16x16x32_bf16(
              afrag[q], bfrag[ni], acc[q][ni], 0, 0, 0);
    }
  };

  STAGE(lds[0], 0);
  STAGE(lds[1], 64);
  WAITVM(NCH);
  __builtin_amdgcn_s_barrier();
  CFENCE();
  COMPUTE(lds[0]);
  #pragma unroll 1
  for (int t = 1; t < NKT; ++t) {
    CFENCE();
    __builtin_amdgcn_s_barrier();
    CFENCE();
    if (t + 1 < NKT) {
      STAGE(lds[(t + 1) & 1], (t + 1) * 64);
      WAITVM(NCH);
    } else {
      WAITVM(0);
    }
    __builtin_amdgcn_s_barrier();
    CFENCE();
    COMPUTE(lds[t & 1]);
  }

  #pragma unroll
  for (int mi = 0; mi < 4; ++mi) {
    const int row0 = m0 + wr * 64 + mi * 16 + hi * 4;
    #pragma unroll
    for (int ni = 0; ni < 4; ++ni) {
      const int col = n0 + wc * 64 + ni * 16 + r16;
      const float bb = b2[l * 768 + col];
      if (MODE == 2) {                  // warm gemm2
        float* Sp = states + (size_t)(l + 1) * LAY_S;
        #pragma unroll
        for (int r = 0; r < 4; ++r)
          Sp[(size_t)(row0 + r) * 768 + col] =
              acc[mi][ni][r] + bb + x0[(size_t)(row0 + r) * 768 + col];
      } else {                          // iter gemm2: row pairs (res, Adiag)
        float* Rp = resA + (size_t)l * LAY_A;
        #pragma unroll
        for (int p = 0; p < 2; ++p) {
          const int tok = (row0 >> 1) + p;
          Rp[(size_t)tok * 768 + col] = acc[mi][ni][2 * p] + bb
              + states[(size_t)l * LAY_S + (size_t)tok * 768 + col]
              - states[(size_t)(l + 1) * LAY_S + (size_t)tok * 768 + col];
          const float vv = (float)vbuf[(size_t)l * LAY_S +
                                       (size_t)tok * 768 + col];
          Rp[LAY_S + (size_t)tok * 768 + col] =
              1.0f + acc[mi][ni][2 * p + 1] * vv;
        }
      }
    }
  }
}

// ------------------------------- LayerNorm ---------------------------------
__global__ __launch_bounds__(256) void ln_warm_kernel(
    const float* __restrict__ x0, const float* __restrict__ g,
    const float* __restrict__ beta, bf16* __restrict__ a_buf)
{
  const int row = blockIdx.x * 4 + (threadIdx.x >> 6);
  const int lane = threadIdx.x & 63;
  const float* x = x0 + (size_t)row * 768;
  float xl[12];
  float s1 = 0.f, s2 = 0.f;
  #pragma unroll
  for (int j = 0; j < 12; ++j) {
    float t = x[lane + 64 * j];
    xl[j] = t; s1 += t; s2 += t * t;
  }
  #pragma unroll
  for (int off = 1; off < 64; off <<= 1) {
    s1 += __shfl_xor(s1, off);
    s2 += __shfl_xor(s2, off);
  }
  const float mu = s1 * (1.f / 768.f);
  const float var = s2 * (1.f / 768.f) - mu * mu;
  const float rstd = rsqrtf(var + 1e-5f);
  float xh[12];
  #pragma unroll
  for (int j = 0; j < 12; ++j) xh[j] = (xl[j] - mu) * rstd;
  for (int l = 0; l < 12; ++l) {
    const float* gp = g + l * 768;
    const float* bp = beta + l * 768;
    bf16* ap = a_buf + (size_t)l * LAY_A + (size_t)row * 768;
    #pragma unroll
    for (int j = 0; j < 12; ++j) {
      const int c = lane + 64 * j;
      ap[c] = (bf16)(xh[j] * gp[c] + bp[c]);
    }
  }
}

__global__ __launch_bounds__(256) void ln_iter_kernel(
    const float* __restrict__ states, bf16* __restrict__ vbuf,
    const float* __restrict__ g, const float* __restrict__ beta,
    bf16* __restrict__ a_buf, uint32_t k1, uint32_t k2)
{
  const int gr = blockIdx.x * 4 + (threadIdx.x >> 6);
  const int l = gr >> 10;
  const int row = gr & 1023;
  const int lane = threadIdx.x & 63;
  const float* x = states + (size_t)l * LAY_S + (size_t)row * 768;
  bf16* vp = vbuf + (size_t)gr * 768;
  float xl[12], vl[12];
  float s1 = 0.f, s2 = 0.f, sv = 0.f, sxv = 0.f;
  #pragma unroll
  for (int j = 0; j < 12; ++j) {
    const int c = lane + 64 * j;
    const float t = x[c];
    uint32_t o0, o1;
    threefry2x32(k1, k2, 0u, (uint32_t)gr * 768u + (uint32_t)c, o0, o1);
    const float u = ((o0 ^ o1) & 0x80000000u) ? 1.0f : -1.0f;
    vp[c] = (bf16)u;
    xl[j] = t; vl[j] = u;
    s1 += t; s2 += t * t; sv += u; sxv += t * u;
  }
  #pragma unroll
  for (int off = 1; off < 64; off <<= 1) {
    s1 += __shfl_xor(s1, off); s2 += __shfl_xor(s2, off);
    sv += __shfl_xor(sv, off); sxv += __shfl_xor(sxv, off);
  }
  const float mu = s1 * (1.f / 768.f);
  const float var = s2 * (1.f / 768.f) - mu * mu;
  const float rstd = rsqrtf(var + 1e-5f);
  const float mv = sv * (1.f / 768.f);
  const float mhv = rstd * (sxv * (1.f / 768.f) - mu * mv);
  const float* gp = g + l * 768;
  const float* bp = beta + l * 768;
  bf16* ap = a_buf + (size_t)l * LAY_A + (size_t)(2 * row) * 768;
  bf16* dp = ap + 768;
  #pragma unroll
  for (int j = 0; j < 12; ++j) {
    const int c = lane + 64 * j;
    const float xh = (xl[j] - mu) * rstd;
    ap[c] = (bf16)(xh * gp[c] + bp[c]);
    dp[c] = (bf16)(rstd * ((vl[j] - mv) - xh * mhv) * gp[c]);
  }
}

// --------------------------- scan + state update ---------------------------
__global__ __launch_bounds__(256) void scan_kernel(
    const float* __restrict__ resA, float* __restrict__ states)
{
  const size_t i = (size_t)blockIdx.x * 256 + threadIdx.x;
  float run = resA[i];
  states[LAY_S + i] += run;
  #pragma unroll
  for (int l = 1; l < 12; ++l) {
    const float b  = resA[(size_t)l * LAY_A + i];
    const float Aa = resA[(size_t)l * LAY_A + LAY_S + i];
    run = b + Aa * run;
    states[(size_t)(l + 1) * LAY_S + i] += run;
  }
}

// ------------------------------- launcher ----------------------------------
extern "C" void kernel_launch(void* const* d_in, const int* in_sizes, int n_in,
                              void* d_out, int out_size, void* d_ws, size_t ws_size,
                              hipStream_t stream)
{
  const float* x0   = (const float*)d_in[0];
  const float* w1   = (const float*)d_in[1];
  const float* b1   = (const float*)d_in[2];
  const float* w2   = (const float*)d_in[3];
  const float* b2   = (const float*)d_in[4];
  const float* g    = (const float*)d_in[5];
  const float* beta = (const float*)d_in[6];

  char* ws = (char*)d_ws;
  size_t off = 0;
  auto alloc = [&](size_t bytes) -> void* {
    void* p = ws + off;
    off += (bytes + 255) & ~(size_t)255;
    return p;
  };
  bf16*  w1t    = (bf16*)alloc(2ULL * 12 * LAY_W);
  bf16*  w2t    = (bf16*)alloc(2ULL * 12 * LAY_W);
  float* states = (float*)alloc(4ULL * 13 * LAY_S);
  bf16*  a_buf  = (bf16*)alloc(2ULL * 12 * LAY_A);
  bf16*  zh     = (bf16*)alloc(2ULL * 12 * LAY_Z);
  float* resA   = (float*)alloc(4ULL * 12 * LAY_A);
  bf16*  vbuf   = (bf16*)alloc(2ULL * 12 * LAY_S);

  transpose_kernel<<<dim3(96, 24, 12), 256, 0, stream>>>(w1, w1t, 768, 3072);
  transpose_kernel<<<dim3(24, 96, 12), 256, 0, stream>>>(w2, w2t, 3072, 768);
  hipMemcpyAsync(states, x0, 4ULL * LAY_S, hipMemcpyDeviceToDevice, stream);

  // warm start: states[l+1] = block_l(x0)
  ln_warm_kernel<<<256, 256, 0, stream>>>(x0, g, beta, a_buf);
  gemm1_8p<0><<<576, 512, 0, stream>>>(a_buf, w1t, zh, b1, 4);
  gemm_dbuf<2><<<576, 256, 0, stream>>>(zh, w2t, states, resA, vbuf, b2, x0, 8);

  for (int it = 0; it < 2; ++it) {
    uint32_t k1, k2;
    threefry2x32(0u, 42u, 0u, (uint32_t)it, k1, k2);
    ln_iter_kernel<<<3072, 256, 0, stream>>>(states, vbuf, g, beta, a_buf,
                                             k1, k2);
    gemm1_8p<1><<<1152, 512, 0, stream>>>(a_buf, w1t, zh, b1, 8);
    gemm_dbuf<3><<<1152, 256, 0, stream>>>(zh, w2t, states, resA, vbuf, b2,
                                           x0, 16);
    scan_kernel<<<3072, 256, 0, stream>>>(resA, states);
  }

  hipMemcpyAsync(d_out, states + 12ULL * LAY_S, 4ULL * LAY_S,
                 hipMemcpyDeviceToDevice, stream);
}

// Round 13
// 1032.884 us; speedup vs baseline: 1.5141x; 1.0185x over previous
//
#include <hip/hip_runtime.h>
#include <hip/hip_bf16.h>
#include <stdint.h>

// ---------------------------------------------------------------------------
// DEER forward, MI355X. L=12, B=2, T=512, C=768, F=3072, M=B*T=1024.
// bf16 MFMA GEMMs (fp32 accum), analytic JVP, threefry2x32 Rademacher v.
// R13: consolidation to measured-best config. GEMM core = true R7 kernel
//      (128x128, 4 waves 2Mx2N, depth-1 counted-vmcnt, 2 blocks/CU,
//      nt-fastest decode, recomputed STAGE addresses) for all 4 modes —
//      every variant tried in R6-R12 (depth-2, nt-stores, mt-decode, BK=32,
//      B-in-reg, 8-phase-with-drain) measured <= this. Launch trims:
//      ln_warm also writes states[0] (drops one d2d memcpy); scan also
//      writes d_out (drops the output memcpy). Numerics unchanged.
// ---------------------------------------------------------------------------

typedef __bf16 bf16;
typedef __bf16 bf16x8 __attribute__((ext_vector_type(8)));
typedef float f32x4 __attribute__((ext_vector_type(4)));

#define LAY_A   1572864   // 2048*768
#define LAY_W   2359296   // 3072*768
#define LAY_Z   6291456   // 2048*3072
#define LAY_S   786432    // 1024*768

#define GLDS16(gp, lp) __builtin_amdgcn_global_load_lds(                      \
    (const __attribute__((address_space(1))) void*)(gp),                      \
    (__attribute__((address_space(3))) void*)(lp), 16, 0, 0)

#define WAITVM(N) asm volatile("s_waitcnt vmcnt(%0)" :: "n"(N) : "memory")
#define CFENCE()  asm volatile("" ::: "memory")

// ------------------------- threefry2x32 (host+device) ----------------------
#define TF_ROT(x0, x1, n) { x0 += x1; x1 = (x1 << n) | (x1 >> (32 - n)); x1 ^= x0; }
__host__ __device__ __forceinline__ void threefry2x32(
    uint32_t k1, uint32_t k2, uint32_t c0, uint32_t c1, uint32_t& o0, uint32_t& o1)
{
  const uint32_t ks2 = k1 ^ k2 ^ 0x1BD11BDAu;
  uint32_t x0 = c0 + k1, x1 = c1 + k2;
  TF_ROT(x0,x1,13) TF_ROT(x0,x1,15) TF_ROT(x0,x1,26) TF_ROT(x0,x1,6)
  x0 += k2;  x1 += ks2 + 1u;
  TF_ROT(x0,x1,17) TF_ROT(x0,x1,29) TF_ROT(x0,x1,16) TF_ROT(x0,x1,24)
  x0 += ks2; x1 += k1 + 2u;
  TF_ROT(x0,x1,13) TF_ROT(x0,x1,15) TF_ROT(x0,x1,26) TF_ROT(x0,x1,6)
  x0 += k1;  x1 += k2 + 3u;
  TF_ROT(x0,x1,17) TF_ROT(x0,x1,29) TF_ROT(x0,x1,16) TF_ROT(x0,x1,24)
  x0 += k2;  x1 += ks2 + 4u;
  TF_ROT(x0,x1,13) TF_ROT(x0,x1,15) TF_ROT(x0,x1,26) TF_ROT(x0,x1,6)
  x0 += ks2; x1 += k1 + 5u;
  o0 = x0; o1 = x1;
}

// --------------------- weight transpose fp32 -> bf16^T ---------------------
__global__ __launch_bounds__(256) void transpose_kernel(
    const float* __restrict__ w, bf16* __restrict__ wt, int R, int Cc)
{
  __shared__ float tile[32][33];
  const int l = blockIdx.z;
  const float* wp = w + (size_t)l * R * Cc;
  bf16* wtp = wt + (size_t)l * R * Cc;
  const int c0 = blockIdx.x * 32;
  const int r0 = blockIdx.y * 32;
  const int tx = threadIdx.x & 31, ty = threadIdx.x >> 5;
  #pragma unroll
  for (int q = 0; q < 4; ++q)
    tile[ty + q * 8][tx] = wp[(size_t)(r0 + ty + q * 8) * Cc + c0 + tx];
  __syncthreads();
  #pragma unroll
  for (int q = 0; q < 4; ++q)
    wtp[(size_t)(c0 + ty + q * 8) * R + r0 + tx] = (bf16)tile[tx][ty + q * 8];
}

// ------------------------------ gelu helper --------------------------------
__device__ __forceinline__ void gelu2(float z, float& h, float& dg)
{
  const float z2 = z * z;
  const float u = 0.7978845608028654f * (z + 0.044715f * z2 * z);
  const float t = tanhf(u);
  h = 0.5f * z * (1.f + t);
  dg = 0.5f * (1.f + t) +
       0.5f * z * (1.f - t * t) * 0.7978845608028654f * (1.f + 0.134145f * z2);
}

// ------------------------------ GEMM core ----------------------------------
// True R7 kernel. 128x128 tile, BK=64, 256 threads = 4 waves (2M x 2N),
// per-wave 64x64 out. Depth-1 counted-vmcnt pipeline over 2 LDS buffers
// (64 KiB -> 2 blocks/CU for cross-block phase overlap).
// MODE 0: gemm1 warm  (M=1024): zh = gelu(acc + b1), all rows.
// MODE 1: gemm1 iter  (M=2048 interleaved): even h=gelu(z), odd dh=dg*dz.
// MODE 2: gemm2 warm : states[l+1] = acc + b2 + x0.
// MODE 3: gemm2 iter  (interleaved): even res, odd A = 1 + acc*v.
template <int MODE>
__global__ __launch_bounds__(256, 2) void gemm_dbuf(
    const bf16* __restrict__ Abase, const bf16* __restrict__ Bbase,
    bf16* __restrict__ zh_out, float* __restrict__ states,
    float* __restrict__ resA, const bf16* __restrict__ vbuf,
    const float* __restrict__ bias1, const float* __restrict__ b2,
    const float* __restrict__ x0, int Mt)
{
  constexpr int LDAB  = (MODE <= 1) ? 768 : 3072;
  constexpr int NKT   = (MODE <= 1) ? 12 : 48;      // K/64
  constexpr int NTN   = (MODE <= 1) ? 24 : 6;       // N/128
  constexpr int ACH   = 16;                 // A chunks (128 rows / 8)
  constexpr int BCH   = 16;                 // B chunks (128 rows / 8)
  constexpr int NCH   = (ACH + BCH) / 4;    // 8 loads per thread per tile
  constexpr int ABYTES = 16384;
  constexpr int TILE  = ABYTES + BCH * 1024;   // 32 KiB
  constexpr size_t LSA = (MODE <= 1) ? LAY_A : LAY_Z;

  __shared__ __align__(16) char lds[2][TILE];  // 64 KiB double buffer

  const int tid  = threadIdx.x;
  const int lane = tid & 63;
  const int wid  = tid >> 6;           // 0..3
  const int wr   = wid >> 1;           // 0..1  (M half)
  const int wc   = wid & 1;            // 0..1  (N half)
  const int r16  = lane & 15;
  const int hi   = lane >> 4;          // 0..3

  // T1: XCD-aware bijective swizzle (grids are multiples of 8)
  const int nwg = gridDim.x;
  const int bid = blockIdx.x;
  const int swz = (bid & 7) * (nwg >> 3) + (bid >> 3);
  const int per_l = Mt * NTN;
  const int l   = swz / per_l;
  const int rr_ = swz - l * per_l;
  const int mt  = rr_ / NTN;
  const int nt  = rr_ - mt * NTN;
  const int m0  = mt * 128, n0 = nt * 128;

  const bf16* A = Abase + (size_t)l * LSA   + (size_t)m0 * LDAB;
  const bf16* B = Bbase + (size_t)l * LAY_W + (size_t)n0 * LDAB;

  const int rsub = lane >> 3;               // 0..7 row within chunk
  const int c8   = (lane & 7) ^ rsub;       // swizzled 16B slot (involution)
  auto STAGE = [&](char* dst, int kt) {
    #pragma unroll
    for (int j = 0; j < NCH; ++j) {
      const int chunk = j * 4 + wid;
      if (chunk < ACH) {
        const int row = chunk * 8 + rsub;
        GLDS16(A + (size_t)row * LDAB + kt + c8 * 8, dst + chunk * 1024);
      } else {
        const int row = (chunk - ACH) * 8 + rsub;
        GLDS16(B + (size_t)row * LDAB + kt + c8 * 8,
               dst + ABYTES + (chunk - ACH) * 1024);
      }
    }
  };

  f32x4 acc[4][4] = {};

  auto COMPUTE = [&](const char* buf) {
    const char* As = buf;
    const char* Bs = buf + ABYTES;
    const int xw = (r16 & 7) << 4;        // read-side XOR (matches staging)
    #pragma unroll
    for (int kk = 0; kk < 2; ++kk) {
      const int cb = kk * 64;
      bf16x8 bfrag[4];
      #pragma unroll
      for (int ni = 0; ni < 4; ++ni) {
        const int rn = wc * 64 + ni * 16 + r16;
        bfrag[ni] = *(const bf16x8*)(Bs + rn * 128 + ((cb + hi * 16) ^ xw));
      }
      bf16x8 afrag[4];
      #pragma unroll
      for (int q = 0; q < 4; ++q) {
        const int rm = wr * 64 + q * 16 + r16;
        afrag[q] = *(const bf16x8*)(As + rm * 128 + ((cb + hi * 16) ^ xw));
      }
      #pragma unroll
      for (int q = 0; q < 4; ++q)
        #pragma unroll
        for (int ni = 0; ni < 4; ++ni)
          acc[q][ni] = __builtin_amdgcn_mfma_f32_16x16x32_bf16(
              afrag[q], bfrag[ni], acc[q][ni], 0, 0, 0);
    }
  };

  // ---- depth-1 counted-vmcnt pipeline (R5-proven) ----
  STAGE(lds[0], 0);
  STAGE(lds[1], 64);
  WAITVM(NCH);                         // tile 0 landed; tile 1 in flight
  __builtin_amdgcn_s_barrier();
  CFENCE();
  COMPUTE(lds[0]);
  #pragma unroll 1
  for (int t = 1; t < NKT; ++t) {
    CFENCE();
    __builtin_amdgcn_s_barrier();      // all waves done reading buf[(t+1)&1]
    CFENCE();
    if (t + 1 < NKT) {
      STAGE(lds[(t + 1) & 1], (t + 1) * 64);
      WAITVM(NCH);                     // tile t landed; t+1 stays in flight
    } else {
      WAITVM(0);                       // last tile: drain
    }
    __builtin_amdgcn_s_barrier();      // cross-wave: tile t visible to all
    CFENCE();
    COMPUTE(lds[t & 1]);
  }

  // ------------------------------ epilogue ---------------------------------
  #pragma unroll
  for (int mi = 0; mi < 4; ++mi) {
    const int row0 = m0 + wr * 64 + mi * 16 + hi * 4;
    #pragma unroll
    for (int ni = 0; ni < 4; ++ni) {
      const int col = n0 + wc * 64 + ni * 16 + r16;
      if (MODE == 0) {                  // warm gemm1: h = gelu(z), all rows
        bf16* Cp = zh_out + (size_t)l * LAY_Z;
        const float bias = bias1[l * 3072 + col];
        #pragma unroll
        for (int r = 0; r < 4; ++r) {
          float h, dg;
          gelu2(acc[mi][ni][r] + bias, h, dg);
          Cp[(size_t)(row0 + r) * 3072 + col] = (bf16)h;
        }
      } else if (MODE == 1) {           // iter gemm1: row pairs (z, dz)
        bf16* Cp = zh_out + (size_t)l * LAY_Z;
        const float bias = bias1[l * 3072 + col];
        #pragma unroll
        for (int p = 0; p < 2; ++p) {
          float h, dg;
          gelu2(acc[mi][ni][2 * p] + bias, h, dg);
          Cp[(size_t)(row0 + 2 * p) * 3072 + col] = (bf16)h;
          Cp[(size_t)(row0 + 2 * p + 1) * 3072 + col] =
              (bf16)(dg * acc[mi][ni][2 * p + 1]);
        }
      } else if (MODE == 2) {           // warm gemm2
        float* Sp = states + (size_t)(l + 1) * LAY_S;
        const float bb = b2[l * 768 + col];
        #pragma unroll
        for (int r = 0; r < 4; ++r)
          Sp[(size_t)(row0 + r) * 768 + col] =
              acc[mi][ni][r] + bb + x0[(size_t)(row0 + r) * 768 + col];
      } else {                          // iter gemm2: row pairs (res, Adiag)
        float* Rp = resA + (size_t)l * LAY_A;
        const float bb = b2[l * 768 + col];
        #pragma unroll
        for (int p = 0; p < 2; ++p) {
          const int tok = (row0 >> 1) + p;          // rows row0+2p, +2p+1
          Rp[(size_t)tok * 768 + col] = acc[mi][ni][2 * p] + bb
              + states[(size_t)l * LAY_S + (size_t)tok * 768 + col]
              - states[(size_t)(l + 1) * LAY_S + (size_t)tok * 768 + col];
          const float vv = (float)vbuf[(size_t)l * LAY_S +
                                       (size_t)tok * 768 + col];
          Rp[LAY_S + (size_t)tok * 768 + col] =
              1.0f + acc[mi][ni][2 * p + 1] * vv;
        }
      }
    }
  }
}

// ------------------------------- LayerNorm ---------------------------------
// warm: writes a_buf for all 12 layers AND copies x0 into states[0]
__global__ __launch_bounds__(256) void ln_warm_kernel(
    const float* __restrict__ x0, const float* __restrict__ g,
    const float* __restrict__ beta, bf16* __restrict__ a_buf,
    float* __restrict__ st0)
{
  const int row = blockIdx.x * 4 + (threadIdx.x >> 6);
  const int lane = threadIdx.x & 63;
  const float* x = x0 + (size_t)row * 768;
  float* s0 = st0 + (size_t)row * 768;
  float xl[12];
  float s1 = 0.f, s2 = 0.f;
  #pragma unroll
  for (int j = 0; j < 12; ++j) {
    float t = x[lane + 64 * j];
    xl[j] = t; s1 += t; s2 += t * t;
    s0[lane + 64 * j] = t;
  }
  #pragma unroll
  for (int off = 1; off < 64; off <<= 1) {
    s1 += __shfl_xor(s1, off);
    s2 += __shfl_xor(s2, off);
  }
  const float mu = s1 * (1.f / 768.f);
  const float var = s2 * (1.f / 768.f) - mu * mu;
  const float rstd = rsqrtf(var + 1e-5f);
  float xh[12];
  #pragma unroll
  for (int j = 0; j < 12; ++j) xh[j] = (xl[j] - mu) * rstd;
  for (int l = 0; l < 12; ++l) {
    const float* gp = g + l * 768;
    const float* bp = beta + l * 768;
    bf16* ap = a_buf + (size_t)l * LAY_A + (size_t)row * 768;
    #pragma unroll
    for (int j = 0; j < 12; ++j) {
      const int c = lane + 64 * j;
      ap[c] = (bf16)(xh[j] * gp[c] + bp[c]);
    }
  }
}

// iter: LN + LN-JVP with tangent v (v generated inline via threefry).
// Writes interleaved rows: token row -> a at 2*row, du at 2*row+1.
__global__ __launch_bounds__(256) void ln_iter_kernel(
    const float* __restrict__ states, bf16* __restrict__ vbuf,
    const float* __restrict__ g, const float* __restrict__ beta,
    bf16* __restrict__ a_buf, uint32_t k1, uint32_t k2)
{
  const int gr = blockIdx.x * 4 + (threadIdx.x >> 6);
  const int l = gr >> 10;
  const int row = gr & 1023;
  const int lane = threadIdx.x & 63;
  const float* x = states + (size_t)l * LAY_S + (size_t)row * 768;
  bf16* vp = vbuf + (size_t)gr * 768;
  float xl[12], vl[12];
  float s1 = 0.f, s2 = 0.f, sv = 0.f, sxv = 0.f;
  #pragma unroll
  for (int j = 0; j < 12; ++j) {
    const int c = lane + 64 * j;
    const float t = x[c];
    uint32_t o0, o1;
    threefry2x32(k1, k2, 0u, (uint32_t)gr * 768u + (uint32_t)c, o0, o1);
    const float u = ((o0 ^ o1) & 0x80000000u) ? 1.0f : -1.0f;
    vp[c] = (bf16)u;
    xl[j] = t; vl[j] = u;
    s1 += t; s2 += t * t; sv += u; sxv += t * u;
  }
  #pragma unroll
  for (int off = 1; off < 64; off <<= 1) {
    s1 += __shfl_xor(s1, off); s2 += __shfl_xor(s2, off);
    sv += __shfl_xor(sv, off); sxv += __shfl_xor(sxv, off);
  }
  const float mu = s1 * (1.f / 768.f);
  const float var = s2 * (1.f / 768.f) - mu * mu;
  const float rstd = rsqrtf(var + 1e-5f);
  const float mv = sv * (1.f / 768.f);
  const float mhv = rstd * (sxv * (1.f / 768.f) - mu * mv);
  const float* gp = g + l * 768;
  const float* bp = beta + l * 768;
  bf16* ap = a_buf + (size_t)l * LAY_A + (size_t)(2 * row) * 768;
  bf16* dp = ap + 768;
  #pragma unroll
  for (int j = 0; j < 12; ++j) {
    const int c = lane + 64 * j;
    const float xh = (xl[j] - mu) * rstd;
    ap[c] = (bf16)(xh * gp[c] + bp[c]);
    dp[c] = (bf16)(rstd * ((vl[j] - mv) - xh * mhv) * gp[c]);
  }
}

// --------------------------- scan + state update ---------------------------
// delta_0 = res_0; delta_l = res_l + A_l*delta_{l-1}; states[l+1] += delta_l.
// Also writes the final layer's state to d_out (saves a d2d copy).
__global__ __launch_bounds__(256) void scan_kernel(
    const float* __restrict__ resA, float* __restrict__ states,
    float* __restrict__ dout)
{
  const size_t i = (size_t)blockIdx.x * 256 + threadIdx.x;
  float run = resA[i];
  float v = states[LAY_S + i] + run;
  states[LAY_S + i] = v;
  #pragma unroll
  for (int l = 1; l < 12; ++l) {
    const float b  = resA[(size_t)l * LAY_A + i];
    const float Aa = resA[(size_t)l * LAY_A + LAY_S + i];
    run = b + Aa * run;
    v = states[(size_t)(l + 1) * LAY_S + i] + run;
    states[(size_t)(l + 1) * LAY_S + i] = v;
  }
  dout[i] = v;                          // states[12] after this update
}

// ------------------------------- launcher ----------------------------------
extern "C" void kernel_launch(void* const* d_in, const int* in_sizes, int n_in,
                              void* d_out, int out_size, void* d_ws, size_t ws_size,
                              hipStream_t stream)
{
  const float* x0   = (const float*)d_in[0];
  const float* w1   = (const float*)d_in[1];
  const float* b1   = (const float*)d_in[2];
  const float* w2   = (const float*)d_in[3];
  const float* b2   = (const float*)d_in[4];
  const float* g    = (const float*)d_in[5];
  const float* beta = (const float*)d_in[6];

  char* ws = (char*)d_ws;
  size_t off = 0;
  auto alloc = [&](size_t bytes) -> void* {
    void* p = ws + off;
    off += (bytes + 255) & ~(size_t)255;
    return p;
  };
  bf16*  w1t    = (bf16*)alloc(2ULL * 12 * LAY_W);
  bf16*  w2t    = (bf16*)alloc(2ULL * 12 * LAY_W);
  float* states = (float*)alloc(4ULL * 13 * LAY_S);
  bf16*  a_buf  = (bf16*)alloc(2ULL * 12 * LAY_A);
  bf16*  zh     = (bf16*)alloc(2ULL * 12 * LAY_Z);
  float* resA   = (float*)alloc(4ULL * 12 * LAY_A);
  bf16*  vbuf   = (bf16*)alloc(2ULL * 12 * LAY_S);

  transpose_kernel<<<dim3(96, 24, 12), 256, 0, stream>>>(w1, w1t, 768, 3072);
  transpose_kernel<<<dim3(24, 96, 12), 256, 0, stream>>>(w2, w2t, 3072, 768);

  // warm start: states[0] = x0 (fused); states[l+1] = block_l(x0)
  ln_warm_kernel<<<256, 256, 0, stream>>>(x0, g, beta, a_buf, states);
  gemm_dbuf<0><<<2304, 256, 0, stream>>>(a_buf, w1t, zh, states, resA, vbuf,
                                         b1, b2, x0, 8);
  gemm_dbuf<2><<<576, 256, 0, stream>>>(zh, w2t, nullptr, states, resA, vbuf,
                                        b1, b2, x0, 8);

  for (int it = 0; it < 2; ++it) {
    uint32_t k1, k2;
    threefry2x32(0u, 42u, 0u, (uint32_t)it, k1, k2);
    ln_iter_kernel<<<3072, 256, 0, stream>>>(states, vbuf, g, beta, a_buf,
                                             k1, k2);
    gemm_dbuf<1><<<4608, 256, 0, stream>>>(a_buf, w1t, zh, states, resA, vbuf,
                                           b1, b2, x0, 16);
    gemm_dbuf<3><<<1152, 256, 0, stream>>>(zh, w2t, nullptr, states, resA, vbuf,
                                           b1, b2, x0, 16);
    scan_kernel<<<3072, 256, 0, stream>>>(resA, states, (float*)d_out);
  }
}

// Round 14
// 992.950 us; speedup vs baseline: 1.5750x; 1.0402x over previous
//
#include <hip/hip_runtime.h>
#include <hip/hip_bf16.h>
#include <stdint.h>

// ---------------------------------------------------------------------------
// DEER forward, MI355X. L=12, B=2, T=512, C=768, F=3072, M=B*T=1024.
// bf16 MFMA GEMMs (fp32 accum), analytic JVP, threefry2x32 Rademacher v.
// R14: R13 (measured-best structure) + two local micro-opts:
//      (a) gelu's tanhf -> native-exp identity t = 1 - 2/(expf(2u)+1)
//          (libm tanhf is ~40cy branchy under -O3; v_exp_f32 path ~8cy;
//          correct limits for u -> +/-inf; error ~1e-7 << bf16 rounding),
//      (b) transpose writes packed bf16x2 (uint) instead of scalar 2B.
//      GEMM core/pipeline byte-identical to R13 (R7 structure).
// ---------------------------------------------------------------------------

typedef __bf16 bf16;
typedef __bf16 bf16x8 __attribute__((ext_vector_type(8)));
typedef float f32x4 __attribute__((ext_vector_type(4)));

#define LAY_A   1572864   // 2048*768
#define LAY_W   2359296   // 3072*768
#define LAY_Z   6291456   // 2048*3072
#define LAY_S   786432    // 1024*768

#define GLDS16(gp, lp) __builtin_amdgcn_global_load_lds(                      \
    (const __attribute__((address_space(1))) void*)(gp),                      \
    (__attribute__((address_space(3))) void*)(lp), 16, 0, 0)

#define WAITVM(N) asm volatile("s_waitcnt vmcnt(%0)" :: "n"(N) : "memory")
#define CFENCE()  asm volatile("" ::: "memory")

// ------------------------- threefry2x32 (host+device) ----------------------
#define TF_ROT(x0, x1, n) { x0 += x1; x1 = (x1 << n) | (x1 >> (32 - n)); x1 ^= x0; }
__host__ __device__ __forceinline__ void threefry2x32(
    uint32_t k1, uint32_t k2, uint32_t c0, uint32_t c1, uint32_t& o0, uint32_t& o1)
{
  const uint32_t ks2 = k1 ^ k2 ^ 0x1BD11BDAu;
  uint32_t x0 = c0 + k1, x1 = c1 + k2;
  TF_ROT(x0,x1,13) TF_ROT(x0,x1,15) TF_ROT(x0,x1,26) TF_ROT(x0,x1,6)
  x0 += k2;  x1 += ks2 + 1u;
  TF_ROT(x0,x1,17) TF_ROT(x0,x1,29) TF_ROT(x0,x1,16) TF_ROT(x0,x1,24)
  x0 += ks2; x1 += k1 + 2u;
  TF_ROT(x0,x1,13) TF_ROT(x0,x1,15) TF_ROT(x0,x1,26) TF_ROT(x0,x1,6)
  x0 += k1;  x1 += k2 + 3u;
  TF_ROT(x0,x1,17) TF_ROT(x0,x1,29) TF_ROT(x0,x1,16) TF_ROT(x0,x1,24)
  x0 += k2;  x1 += ks2 + 4u;
  TF_ROT(x0,x1,13) TF_ROT(x0,x1,15) TF_ROT(x0,x1,26) TF_ROT(x0,x1,6)
  x0 += ks2; x1 += k1 + 5u;
  o0 = x0; o1 = x1;
}

// --------------------- weight transpose fp32 -> bf16^T ---------------------
__global__ __launch_bounds__(256) void transpose_kernel(
    const float* __restrict__ w, bf16* __restrict__ wt, int R, int Cc)
{
  __shared__ float tile[32][33];
  const int l = blockIdx.z;
  const float* wp = w + (size_t)l * R * Cc;
  bf16* wtp = wt + (size_t)l * R * Cc;
  const int c0 = blockIdx.x * 32;
  const int r0 = blockIdx.y * 32;
  const int tx = threadIdx.x & 31, ty = threadIdx.x >> 5;
  #pragma unroll
  for (int q = 0; q < 4; ++q)
    tile[ty + q * 8][tx] = wp[(size_t)(r0 + ty + q * 8) * Cc + c0 + tx];
  __syncthreads();
  // packed bf16x2 stores: thread -> 2 output rows x 2 consecutive cols
  const int orow = threadIdx.x >> 4;        // 0..15
  const int oc   = (threadIdx.x & 15) * 2;  // even col
  #pragma unroll
  for (int q = 0; q < 2; ++q) {
    const int r = orow + q * 16;
    const unsigned short lo = __builtin_bit_cast(unsigned short,
                                                 (bf16)tile[oc][r]);
    const unsigned short hi = __builtin_bit_cast(unsigned short,
                                                 (bf16)tile[oc + 1][r]);
    *(unsigned int*)&wtp[(size_t)(c0 + r) * R + r0 + oc] =
        (unsigned int)lo | ((unsigned int)hi << 16);
  }
}

// ------------------------------ gelu helper --------------------------------
// tanh via native exp: t = 1 - 2/(e^{2u}+1). Limits: u->+inf: t->1;
// u->-inf: e->0, t->-1. |err| ~1e-7 (<< bf16 output rounding).
__device__ __forceinline__ void gelu2(float z, float& h, float& dg)
{
  const float z2 = z * z;
  const float u = 0.7978845608028654f * (z + 0.044715f * z2 * z);
  const float e = __expf(2.0f * u);
  const float t = 1.0f - 2.0f / (e + 1.0f);
  h = 0.5f * z * (1.f + t);
  dg = 0.5f * (1.f + t) +
       0.5f * z * (1.f - t * t) * 0.7978845608028654f * (1.f + 0.134145f * z2);
}

// ------------------------------ GEMM core ----------------------------------
// True R7 kernel. 128x128 tile, BK=64, 256 threads = 4 waves (2M x 2N),
// per-wave 64x64 out. Depth-1 counted-vmcnt pipeline over 2 LDS buffers
// (64 KiB -> 2 blocks/CU for cross-block phase overlap).
// MODE 0: gemm1 warm  (M=1024): zh = gelu(acc + b1), all rows.
// MODE 1: gemm1 iter  (M=2048 interleaved): even h=gelu(z), odd dh=dg*dz.
// MODE 2: gemm2 warm : states[l+1] = acc + b2 + x0.
// MODE 3: gemm2 iter  (interleaved): even res, odd A = 1 + acc*v.
template <int MODE>
__global__ __launch_bounds__(256, 2) void gemm_dbuf(
    const bf16* __restrict__ Abase, const bf16* __restrict__ Bbase,
    bf16* __restrict__ zh_out, float* __restrict__ states,
    float* __restrict__ resA, const bf16* __restrict__ vbuf,
    const float* __restrict__ bias1, const float* __restrict__ b2,
    const float* __restrict__ x0, int Mt)
{
  constexpr int LDAB  = (MODE <= 1) ? 768 : 3072;
  constexpr int NKT   = (MODE <= 1) ? 12 : 48;      // K/64
  constexpr int NTN   = (MODE <= 1) ? 24 : 6;       // N/128
  constexpr int ACH   = 16;                 // A chunks (128 rows / 8)
  constexpr int BCH   = 16;                 // B chunks (128 rows / 8)
  constexpr int NCH   = (ACH + BCH) / 4;    // 8 loads per thread per tile
  constexpr int ABYTES = 16384;
  constexpr int TILE  = ABYTES + BCH * 1024;   // 32 KiB
  constexpr size_t LSA = (MODE <= 1) ? LAY_A : LAY_Z;

  __shared__ __align__(16) char lds[2][TILE];  // 64 KiB double buffer

  const int tid  = threadIdx.x;
  const int lane = tid & 63;
  const int wid  = tid >> 6;           // 0..3
  const int wr   = wid >> 1;           // 0..1  (M half)
  const int wc   = wid & 1;            // 0..1  (N half)
  const int r16  = lane & 15;
  const int hi   = lane >> 4;          // 0..3

  // T1: XCD-aware bijective swizzle (grids are multiples of 8)
  const int nwg = gridDim.x;
  const int bid = blockIdx.x;
  const int swz = (bid & 7) * (nwg >> 3) + (bid >> 3);
  const int per_l = Mt * NTN;
  const int l   = swz / per_l;
  const int rr_ = swz - l * per_l;
  const int mt  = rr_ / NTN;
  const int nt  = rr_ - mt * NTN;
  const int m0  = mt * 128, n0 = nt * 128;

  const bf16* A = Abase + (size_t)l * LSA   + (size_t)m0 * LDAB;
  const bf16* B = Bbase + (size_t)l * LAY_W + (size_t)n0 * LDAB;

  const int rsub = lane >> 3;               // 0..7 row within chunk
  const int c8   = (lane & 7) ^ rsub;       // swizzled 16B slot (involution)
  auto STAGE = [&](char* dst, int kt) {
    #pragma unroll
    for (int j = 0; j < NCH; ++j) {
      const int chunk = j * 4 + wid;
      if (chunk < ACH) {
        const int row = chunk * 8 + rsub;
        GLDS16(A + (size_t)row * LDAB + kt + c8 * 8, dst + chunk * 1024);
      } else {
        const int row = (chunk - ACH) * 8 + rsub;
        GLDS16(B + (size_t)row * LDAB + kt + c8 * 8,
               dst + ABYTES + (chunk - ACH) * 1024);
      }
    }
  };

  f32x4 acc[4][4] = {};

  auto COMPUTE = [&](const char* buf) {
    const char* As = buf;
    const char* Bs = buf + ABYTES;
    const int xw = (r16 & 7) << 4;        // read-side XOR (matches staging)
    #pragma unroll
    for (int kk = 0; kk < 2; ++kk) {
      const int cb = kk * 64;
      bf16x8 bfrag[4];
      #pragma unroll
      for (int ni = 0; ni < 4; ++ni) {
        const int rn = wc * 64 + ni * 16 + r16;
        bfrag[ni] = *(const bf16x8*)(Bs + rn * 128 + ((cb + hi * 16) ^ xw));
      }
      bf16x8 afrag[4];
      #pragma unroll
      for (int q = 0; q < 4; ++q) {
        const int rm = wr * 64 + q * 16 + r16;
        afrag[q] = *(const bf16x8*)(As + rm * 128 + ((cb + hi * 16) ^ xw));
      }
      #pragma unroll
      for (int q = 0; q < 4; ++q)
        #pragma unroll
        for (int ni = 0; ni < 4; ++ni)
          acc[q][ni] = __builtin_amdgcn_mfma_f32_16x16x32_bf16(
              afrag[q], bfrag[ni], acc[q][ni], 0, 0, 0);
    }
  };

  // ---- depth-1 counted-vmcnt pipeline (R5-proven) ----
  STAGE(lds[0], 0);
  STAGE(lds[1], 64);
  WAITVM(NCH);                         // tile 0 landed; tile 1 in flight
  __builtin_amdgcn_s_barrier();
  CFENCE();
  COMPUTE(lds[0]);
  #pragma unroll 1
  for (int t = 1; t < NKT; ++t) {
    CFENCE();
    __builtin_amdgcn_s_barrier();      // all waves done reading buf[(t+1)&1]
    CFENCE();
    if (t + 1 < NKT) {
      STAGE(lds[(t + 1) & 1], (t + 1) * 64);
      WAITVM(NCH);                     // tile t landed; t+1 stays in flight
    } else {
      WAITVM(0);                       // last tile: drain
    }
    __builtin_amdgcn_s_barrier();      // cross-wave: tile t visible to all
    CFENCE();
    COMPUTE(lds[t & 1]);
  }

  // ------------------------------ epilogue ---------------------------------
  #pragma unroll
  for (int mi = 0; mi < 4; ++mi) {
    const int row0 = m0 + wr * 64 + mi * 16 + hi * 4;
    #pragma unroll
    for (int ni = 0; ni < 4; ++ni) {
      const int col = n0 + wc * 64 + ni * 16 + r16;
      if (MODE == 0) {                  // warm gemm1: h = gelu(z), all rows
        bf16* Cp = zh_out + (size_t)l * LAY_Z;
        const float bias = bias1[l * 3072 + col];
        #pragma unroll
        for (int r = 0; r < 4; ++r) {
          float h, dg;
          gelu2(acc[mi][ni][r] + bias, h, dg);
          Cp[(size_t)(row0 + r) * 3072 + col] = (bf16)h;
        }
      } else if (MODE == 1) {           // iter gemm1: row pairs (z, dz)
        bf16* Cp = zh_out + (size_t)l * LAY_Z;
        const float bias = bias1[l * 3072 + col];
        #pragma unroll
        for (int p = 0; p < 2; ++p) {
          float h, dg;
          gelu2(acc[mi][ni][2 * p] + bias, h, dg);
          Cp[(size_t)(row0 + 2 * p) * 3072 + col] = (bf16)h;
          Cp[(size_t)(row0 + 2 * p + 1) * 3072 + col] =
              (bf16)(dg * acc[mi][ni][2 * p + 1]);
        }
      } else if (MODE == 2) {           // warm gemm2
        float* Sp = states + (size_t)(l + 1) * LAY_S;
        const float bb = b2[l * 768 + col];
        #pragma unroll
        for (int r = 0; r < 4; ++r)
          Sp[(size_t)(row0 + r) * 768 + col] =
              acc[mi][ni][r] + bb + x0[(size_t)(row0 + r) * 768 + col];
      } else {                          // iter gemm2: row pairs (res, Adiag)
        float* Rp = resA + (size_t)l * LAY_A;
        const float bb = b2[l * 768 + col];
        #pragma unroll
        for (int p = 0; p < 2; ++p) {
          const int tok = (row0 >> 1) + p;          // rows row0+2p, +2p+1
          Rp[(size_t)tok * 768 + col] = acc[mi][ni][2 * p] + bb
              + states[(size_t)l * LAY_S + (size_t)tok * 768 + col]
              - states[(size_t)(l + 1) * LAY_S + (size_t)tok * 768 + col];
          const float vv = (float)vbuf[(size_t)l * LAY_S +
                                       (size_t)tok * 768 + col];
          Rp[LAY_S + (size_t)tok * 768 + col] =
              1.0f + acc[mi][ni][2 * p + 1] * vv;
        }
      }
    }
  }
}

// ------------------------------- LayerNorm ---------------------------------
// warm: writes a_buf for all 12 layers AND copies x0 into states[0]
__global__ __launch_bounds__(256) void ln_warm_kernel(
    const float* __restrict__ x0, const float* __restrict__ g,
    const float* __restrict__ beta, bf16* __restrict__ a_buf,
    float* __restrict__ st0)
{
  const int row = blockIdx.x * 4 + (threadIdx.x >> 6);
  const int lane = threadIdx.x & 63;
  const float* x = x0 + (size_t)row * 768;
  float* s0 = st0 + (size_t)row * 768;
  float xl[12];
  float s1 = 0.f, s2 = 0.f;
  #pragma unroll
  for (int j = 0; j < 12; ++j) {
    float t = x[lane + 64 * j];
    xl[j] = t; s1 += t; s2 += t * t;
    s0[lane + 64 * j] = t;
  }
  #pragma unroll
  for (int off = 1; off < 64; off <<= 1) {
    s1 += __shfl_xor(s1, off);
    s2 += __shfl_xor(s2, off);
  }
  const float mu = s1 * (1.f / 768.f);
  const float var = s2 * (1.f / 768.f) - mu * mu;
  const float rstd = rsqrtf(var + 1e-5f);
  float xh[12];
  #pragma unroll
  for (int j = 0; j < 12; ++j) xh[j] = (xl[j] - mu) * rstd;
  for (int l = 0; l < 12; ++l) {
    const float* gp = g + l * 768;
    const float* bp = beta + l * 768;
    bf16* ap = a_buf + (size_t)l * LAY_A + (size_t)row * 768;
    #pragma unroll
    for (int j = 0; j < 12; ++j) {
      const int c = lane + 64 * j;
      ap[c] = (bf16)(xh[j] * gp[c] + bp[c]);
    }
  }
}

// iter: LN + LN-JVP with tangent v (v generated inline via threefry).
// Writes interleaved rows: token row -> a at 2*row, du at 2*row+1.
__global__ __launch_bounds__(256) void ln_iter_kernel(
    const float* __restrict__ states, bf16* __restrict__ vbuf,
    const float* __restrict__ g, const float* __restrict__ beta,
    bf16* __restrict__ a_buf, uint32_t k1, uint32_t k2)
{
  const int gr = blockIdx.x * 4 + (threadIdx.x >> 6);
  const int l = gr >> 10;
  const int row = gr & 1023;
  const int lane = threadIdx.x & 63;
  const float* x = states + (size_t)l * LAY_S + (size_t)row * 768;
  bf16* vp = vbuf + (size_t)gr * 768;
  float xl[12], vl[12];
  float s1 = 0.f, s2 = 0.f, sv = 0.f, sxv = 0.f;
  #pragma unroll
  for (int j = 0; j < 12; ++j) {
    const int c = lane + 64 * j;
    const float t = x[c];
    uint32_t o0, o1;
    threefry2x32(k1, k2, 0u, (uint32_t)gr * 768u + (uint32_t)c, o0, o1);
    const float u = ((o0 ^ o1) & 0x80000000u) ? 1.0f : -1.0f;
    vp[c] = (bf16)u;
    xl[j] = t; vl[j] = u;
    s1 += t; s2 += t * t; sv += u; sxv += t * u;
  }
  #pragma unroll
  for (int off = 1; off < 64; off <<= 1) {
    s1 += __shfl_xor(s1, off); s2 += __shfl_xor(s2, off);
    sv += __shfl_xor(sv, off); sxv += __shfl_xor(sxv, off);
  }
  const float mu = s1 * (1.f / 768.f);
  const float var = s2 * (1.f / 768.f) - mu * mu;
  const float rstd = rsqrtf(var + 1e-5f);
  const float mv = sv * (1.f / 768.f);
  const float mhv = rstd * (sxv * (1.f / 768.f) - mu * mv);
  const float* gp = g + l * 768;
  const float* bp = beta + l * 768;
  bf16* ap = a_buf + (size_t)l * LAY_A + (size_t)(2 * row) * 768;
  bf16* dp = ap + 768;
  #pragma unroll
  for (int j = 0; j < 12; ++j) {
    const int c = lane + 64 * j;
    const float xh = (xl[j] - mu) * rstd;
    ap[c] = (bf16)(xh * gp[c] + bp[c]);
    dp[c] = (bf16)(rstd * ((vl[j] - mv) - xh * mhv) * gp[c]);
  }
}

// --------------------------- scan + state update ---------------------------
// delta_0 = res_0; delta_l = res_l + A_l*delta_{l-1}; states[l+1] += delta_l.
// Also writes the final layer's state to d_out (saves a d2d copy).
__global__ __launch_bounds__(256) void scan_kernel(
    const float* __restrict__ resA, float* __restrict__ states,
    float* __restrict__ dout)
{
  const size_t i = (size_t)blockIdx.x * 256 + threadIdx.x;
  float run = resA[i];
  float v = states[LAY_S + i] + run;
  states[LAY_S + i] = v;
  #pragma unroll
  for (int l = 1; l < 12; ++l) {
    const float b  = resA[(size_t)l * LAY_A + i];
    const float Aa = resA[(size_t)l * LAY_A + LAY_S + i];
    run = b + Aa * run;
    v = states[(size_t)(l + 1) * LAY_S + i] + run;
    states[(size_t)(l + 1) * LAY_S + i] = v;
  }
  dout[i] = v;                          // states[12] after this update
}

// ------------------------------- launcher ----------------------------------
extern "C" void kernel_launch(void* const* d_in, const int* in_sizes, int n_in,
                              void* d_out, int out_size, void* d_ws, size_t ws_size,
                              hipStream_t stream)
{
  const float* x0   = (const float*)d_in[0];
  const float* w1   = (const float*)d_in[1];
  const float* b1   = (const float*)d_in[2];
  const float* w2   = (const float*)d_in[3];
  const float* b2   = (const float*)d_in[4];
  const float* g    = (const float*)d_in[5];
  const float* beta = (const float*)d_in[6];

  char* ws = (char*)d_ws;
  size_t off = 0;
  auto alloc = [&](size_t bytes) -> void* {
    void* p = ws + off;
    off += (bytes + 255) & ~(size_t)255;
    return p;
  };
  bf16*  w1t    = (bf16*)alloc(2ULL * 12 * LAY_W);
  bf16*  w2t    = (bf16*)alloc(2ULL * 12 * LAY_W);
  float* states = (float*)alloc(4ULL * 13 * LAY_S);
  bf16*  a_buf  = (bf16*)alloc(2ULL * 12 * LAY_A);
  bf16*  zh     = (bf16*)alloc(2ULL * 12 * LAY_Z);
  float* resA   = (float*)alloc(4ULL * 12 * LAY_A);
  bf16*  vbuf   = (bf16*)alloc(2ULL * 12 * LAY_S);

  transpose_kernel<<<dim3(96, 24, 12), 256, 0, stream>>>(w1, w1t, 768, 3072);
  transpose_kernel<<<dim3(24, 96, 12), 256, 0, stream>>>(w2, w2t, 3072, 768);

  // warm start: states[0] = x0 (fused); states[l+1] = block_l(x0)
  ln_warm_kernel<<<256, 256, 0, stream>>>(x0, g, beta, a_buf, states);
  gemm_dbuf<0><<<2304, 256, 0, stream>>>(a_buf, w1t, zh, states, resA, vbuf,
                                         b1, b2, x0, 8);
  gemm_dbuf<2><<<576, 256, 0, stream>>>(zh, w2t, nullptr, states, resA, vbuf,
                                        b1, b2, x0, 8);

  for (int it = 0; it < 2; ++it) {
    uint32_t k1, k2;
    threefry2x32(0u, 42u, 0u, (uint32_t)it, k1, k2);
    ln_iter_kernel<<<3072, 256, 0, stream>>>(states, vbuf, g, beta, a_buf,
                                             k1, k2);
    gemm_dbuf<1><<<4608, 256, 0, stream>>>(a_buf, w1t, zh, states, resA, vbuf,
                                           b1, b2, x0, 16);
    gemm_dbuf<3><<<1152, 256, 0, stream>>>(zh, w2t, nullptr, states, resA, vbuf,
                                           b1, b2, x0, 16);
    scan_kernel<<<3072, 256, 0, stream>>>(resA, states, (float*)d_out);
  }
}